// Round 11
// baseline (78.585 us; speedup 1.0000x reference)
//
#include <hip/hip_runtime.h>
#include <math.h>

#define NF    256
#define NSUB  512
#define NB    1024
#define NITER 128          // AABB iterations
#define PI4   0.78539816339744830962f

// ws layout (floats):
//   [0 .. 131071]    compressed coef blob: float4 index = t*256 + k*64 + lane
//                    k=0: AA slot 2l, k=1: AA slot 2l+1, k=2: BB slot 2l, k=3: BB slot 2l+1
//                    each float4 = (cos(th1)/2, sin(th1)/2, (cos(th2)+1)/2, sin(th2)/2)
//   [131072..131583] ps table: 256 x float2 (cos ps, sin ps)
//   [131584]         flag (uint): 0 = fast path valid (split==0 && atten==1 verified)
#define PS_OFF   (NITER * 1024)
#define FLAG_OFF (PS_OFF + 512)
#define WS_REQ   ((size_t)(FLAG_OFF + 1) * sizeof(float))

// ---- pointer-content probes (validated R6-R10) -----------------------------
__device__ __forceinline__ bool looks_zero(const void* p) {
  const unsigned* u = (const unsigned*)p;
  return (u[1] | u[25] | u[111]) == 0u;
}
__device__ __forceinline__ bool looks_ones(const void* p) {
  const unsigned* u = (const unsigned*)p;
  return u[1] == 0x3F800000u && u[3] == 0x3F800000u && u[257] == 0x3F800000u;
}

// ---- DPP wave shifts: VALU-latency lane+-1 exchange (gfx9-lineage) ---------
// wave_shl:1 (0x130): lane i <- lane i+1   (== __shfl_down(x,1))
// wave_shr:1 (0x138): lane i <- lane i-1   (== __shfl_up(x,1))
__device__ __forceinline__ float dpp_shl1(float x) {
  return __int_as_float(
      __builtin_amdgcn_mov_dpp(__float_as_int(x), 0x130, 0xF, 0xF, true));
}
__device__ __forceinline__ float dpp_shr1(float x) {
  return __int_as_float(
      __builtin_amdgcn_mov_dpp(__float_as_int(x), 0x138, 0xF, 0xF, true));
}

// ---- flag init + full structural verification ------------------------------
__global__ void flag_init_kernel(float* ws) {
  ((unsigned*)ws)[FLAG_OFF] = 0u;
}

__global__ __launch_bounds__(256) void check_kernel(
    const void* __restrict__ pp0, const void* __restrict__ pp1,
    const void* __restrict__ pi0, const void* __restrict__ pi1,
    float* __restrict__ ws) {
  const unsigned* split = (const unsigned*)(looks_zero(pp0) ? pp0 : pp1);
  const unsigned* atten = (const unsigned*)(looks_ones(pi0) ? pi0 : pi1);
  const int i = blockIdx.x * 256 + threadIdx.x;   // 0 .. 131071
  unsigned bad = 0u;
  if (atten[i] != 0x3F800000u) bad = 1u;
  if (i < 65536 && split[i] != 0u) bad = 1u;
  if (bad) atomicOr(((unsigned*)ws) + FLAG_OFF, 1u);
}

// ---- precompute: compressed (E1/2, (E2+1)/2) per pair slot -----------------
__global__ __launch_bounds__(256) void precompute3_kernel(
    const void* __restrict__ pp0, const void* __restrict__ pp1,
    const float* __restrict__ psp, float* __restrict__ ws) {
  const float* params = looks_zero(pp0) ? (const float*)pp1 : (const float*)pp0;
  const int t = blockIdx.x;
  const int j = threadIdx.x;
  if (t == NITER) {  // ps table
    float sn, cs;
    sincosf(psp[j], &sn, &cs);
    ((float2*)(ws + PS_OFF))[j] = make_float2(cs, sn);
    return;
  }
  float e1r, e1i, fr, fi;
  int k, ln;
  if (j < 128) {            // AA slot j : sublayers 4t, 4t+1, pair index j
    float s1, c1, s2, c2;
    sincosf(params[(size_t)(4 * t) * 128 + j], &s1, &c1);
    sincosf(params[(size_t)(4 * t + 1) * 128 + j], &s2, &c2);
    e1r = 0.5f * c1; e1i = 0.5f * s1;
    fr = 0.5f * (c2 + 1.f); fi = 0.5f * s2;
    k = j & 1; ln = j >> 1;
  } else {                  // BB slot m : sublayers 4t+2, 4t+3
    const int m = j - 128;
    if (m < 127) {
      float s1, c1, s2, c2;
      sincosf(params[(size_t)(4 * t + 2) * 128 + m], &s1, &c1);
      sincosf(params[(size_t)(4 * t + 3) * 128 + m], &s2, &c2);
      e1r = 0.5f * c1; e1i = 0.5f * s1;
      fr = 0.5f * (c2 + 1.f); fi = 0.5f * s2;
    } else {                // pad slot -> identity (E1=-1, E2=-1)
      e1r = -0.5f; e1i = 0.f; fr = 0.f; fi = 0.f;
    }
    k = 2 + (m & 1); ln = m >> 1;
  }
  ((float4*)ws)[t * 256 + k * 64 + ln] = make_float4(e1r, e1i, fr, fi);
}

// ---- compressed combined-MZI apply -----------------------------------------
// K = (E1r/2, E1i/2, (E2r+1)/2, E2i/2); C = M(th2)M(th1), t=r=1/sqrt2:
// u' = (z - w) + i F v ;  v' = i (z + w) + (v - F v)
// with w = (E1/2) u, z = E2 w, F = (E2+1)/2.
__device__ __forceinline__ void applyC(float& ur, float& ui, float& vr, float& vi,
                                       const float4 K) {
  const float wr = K.x * ur - K.y * ui;
  const float wi = K.x * ui + K.y * ur;
  const float e2r = 2.f * K.z - 1.f;
  const float e2i = 2.f * K.w;
  const float zr = e2r * wr - e2i * wi;
  const float zi = e2r * wi + e2i * wr;
  const float gr = K.z * vr - K.w * vi;   // F v
  const float gi = K.z * vi + K.w * vr;
  const float nur = (zr - wr) - gi;
  const float nui = (zi - wi) + gr;
  const float nvr = (vr - gr) - (zi + wi);
  const float nvi = (vi - gi) + (zr + wr);
  ur = nur; ui = nui; vr = nvr; vi = nvi;
}

// ---- general fallback pieces (only if check fails; never in practice) ------
__device__ __forceinline__ void mzi(float& ur, float& ui, float& vr, float& vi,
                                    const float4 k) {
  const float c = k.x, s = k.y, t = k.z, r = k.w;
  const float pr  = c * ur - s * ui;
  const float pi_ = s * ur + c * ui;
  const float nur = t * pr  - r * vi;
  const float nui = t * pi_ + r * vr;
  const float nvr = t * vr - r * pi_;
  const float nvi = t * vi + r * pr;
  ur = nur; ui = nui; vr = nvr; vi = nvi;
}
struct Coef { float4 a, b, c; };
__device__ __forceinline__ Coef makeCoefRaw(const float* params, const float* split,
                                            const float* atten, int s, int lane) {
  Coef k;
  const float2 th = *(const float2*)(params + (size_t)s * 128 + 2 * lane);
  const float2 sp = *(const float2*)(split + (size_t)s * 128 + 2 * lane);
  k.c = *(const float4*)(atten + (size_t)s * NF + 4 * lane);
  float sn, cs, rr, tt;
  sincosf(th.x, &sn, &cs);
  sincosf(PI4 + sp.x, &rr, &tt);
  k.a = make_float4(cs, sn, tt, rr);
  sincosf(th.y, &sn, &cs);
  sincosf(PI4 + sp.y, &rr, &tt);
  k.b = make_float4(cs, sn, tt, rr);
  return k;
}

// one AABB block (4 sublayers) on registers; DPP for the +-1 lane exchange
#define ITER_BODY(C0, C1, C2, C3)                                          \
  {                                                                        \
    applyC(x0r, x0i, x1r, x1i, C0);                                        \
    applyC(x2r, x2i, x3r, x3i, C1);                                        \
    const float s0r = x0r, s0i = x0i;                                      \
    const float d3r = dpp_shl1(x0r), d3i = dpp_shl1(x0i);                  \
    x0r = x1r; x0i = x1i; x1r = x2r; x1i = x2i; x2r = x3r; x2i = x3i;      \
    x3r = d3r; x3i = d3i;                                                  \
    applyC(x0r, x0i, x1r, x1i, C2);                                        \
    applyC(x2r, x2i, x3r, x3i, C3);                                        \
    const float u0r = dpp_shr1(x3r), u0i = dpp_shr1(x3i);                  \
    x3r = x2r; x3i = x2i; x2r = x1r; x2i = x1i; x1r = x0r; x1i = x0i;      \
    x0r = lane ? u0r : s0r;                                                \
    x0i = lane ? u0i : s0i;                                                \
  }

__global__ __launch_bounds__(256) void mesh3_kernel(
    const float* __restrict__ xr_in, const float* __restrict__ xi_in,
    const float* __restrict__ ws,
    const void* __restrict__ pp0, const void* __restrict__ pp1,
    const void* __restrict__ pi0, const void* __restrict__ pi1,
    const float* __restrict__ psp,
    float* __restrict__ out) {
  const int lane = threadIdx.x & 63;
  const int wv   = threadIdx.x >> 6;
  const int row  = blockIdx.x * 4 + wv;   // one wave per batch row

  const float4 r4 = ((const float4*)(xr_in + (size_t)row * NF))[lane];
  const float4 i4 = ((const float4*)(xi_in + (size_t)row * NF))[lane];
  float x0r = r4.x, x1r = r4.y, x2r = r4.z, x3r = r4.w;
  float x0i = i4.x, x1i = i4.y, x2i = i4.z, x3i = i4.w;

  const unsigned flag = ((const unsigned*)ws)[FLAG_OFF];
  if (flag == 0u) {
    // -------- fast path: compressed coefs, direct-load dbuf, DPP shifts ----
    const float4* cb = (const float4*)ws + lane;
    float4 A0 = cb[0],   A1 = cb[64],  A2 = cb[128], A3 = cb[192];   // iter 0
    float4 B0 = cb[256], B1 = cb[320], B2 = cb[384], B3 = cb[448];   // iter 1
#pragma unroll 1
    for (int tt = 0; tt < 64; ++tt) {
      // iter 2tt consumes A; then A is reloaded with iter 2tt+2 (distance 2)
      ITER_BODY(A0, A1, A2, A3);
      {
        const int pa = (tt < 63) ? (2 * tt + 2) * 256 : 0;   // dummy at tail
        A0 = cb[pa]; A1 = cb[pa + 64]; A2 = cb[pa + 128]; A3 = cb[pa + 192];
      }
      ITER_BODY(B0, B1, B2, B3);
      {
        const int pb = (tt < 63) ? (2 * tt + 3) * 256 : 0;
        B0 = cb[pb]; B1 = cb[pb + 64]; B2 = cb[pb + 128]; B3 = cb[pb + 192];
      }
    }
    // epilogue from ps table
    const float2* psc = (const float2*)(ws + PS_OFF);
    const float2 p0 = psc[4 * lane + 0];
    const float2 p1 = psc[4 * lane + 1];
    const float2 p2 = psc[4 * lane + 2];
    const float2 p3 = psc[4 * lane + 3];
    const float o0r = x0r * p0.x - x0i * p0.y, o0i = x0r * p0.y + x0i * p0.x;
    const float o1r = x1r * p1.x - x1i * p1.y, o1i = x1r * p1.y + x1i * p1.x;
    const float o2r = x2r * p2.x - x2i * p2.y, o2i = x2r * p2.y + x2i * p2.x;
    const float o3r = x3r * p3.x - x3i * p3.y, o3i = x3r * p3.y + x3i * p3.x;
    float4* op = (float4*)out;
    const size_t base = (size_t)row * 64 + lane;
    op[base] = make_float4(o0r, o1r, o2r, o3r);
    op[(size_t)NB * 64 + base] = make_float4(o0i, o1i, o2i, o3i);
    return;
  }

  // -------- general fallback: per-sublayer from raw inputs ------------------
  {
    const float* params = looks_zero(pp0) ? (const float*)pp1 : (const float*)pp0;
    const float* split  = looks_zero(pp0) ? (const float*)pp0 : (const float*)pp1;
    const float* atten  = looks_ones(pi0) ? (const float*)pi0 : (const float*)pi1;
#pragma unroll 1
    for (int s = 0; s < NSUB; s += 4) {
      {  // A layer s
        Coef k = makeCoefRaw(params, split, atten, s, lane);
        mzi(x0r, x0i, x1r, x1i, k.a);
        mzi(x2r, x2i, x3r, x3i, k.b);
        x0r *= k.c.x; x0i *= k.c.x; x1r *= k.c.y; x1i *= k.c.y;
        x2r *= k.c.z; x2i *= k.c.z; x3r *= k.c.w; x3i *= k.c.w;
      }
      {  // A layer s+1
        Coef k = makeCoefRaw(params, split, atten, s + 1, lane);
        mzi(x0r, x0i, x1r, x1i, k.a);
        mzi(x2r, x2i, x3r, x3i, k.b);
        x0r *= k.c.x; x0i *= k.c.x; x1r *= k.c.y; x1i *= k.c.y;
        x2r *= k.c.z; x2i *= k.c.z; x3r *= k.c.w; x3i *= k.c.w;
      }
#pragma unroll
      for (int q = 2; q < 4; ++q) {  // B layers s+2, s+3
        Coef k = makeCoefRaw(params, split, atten, s + q, lane);
        mzi(x1r, x1i, x2r, x2i, k.a);
        const float nvr = __shfl_down(x0r, 1);
        const float nvi = __shfl_down(x0i, 1);
        const float c = k.b.x, sv = k.b.y, t = k.b.z, r = k.b.w;
        const float pr  = c * x3r - sv * x3i;
        const float pi_ = sv * x3r + c * x3i;
        const float yur = t * pr  - r * nvi;
        const float yui = t * pi_ + r * nvr;
        const float yvr = t * nvr - r * pi_;
        const float yvi = t * nvi + r * pr;
        const float svr = __shfl_up(yvr, 1);
        const float svi = __shfl_up(yvi, 1);
        if (lane < 63) { x3r = yur; x3i = yui; }
        if (lane > 0)  { x0r = svr; x0i = svi; }
        x0r *= k.c.x; x0i *= k.c.x; x1r *= k.c.y; x1i *= k.c.y;
        x2r *= k.c.z; x2i *= k.c.z; x3r *= k.c.w; x3i *= k.c.w;
      }
    }
    float c0, s0, c1, s1, c2, s2, c3, s3;
    sincosf(psp[4 * lane + 0], &s0, &c0);
    sincosf(psp[4 * lane + 1], &s1, &c1);
    sincosf(psp[4 * lane + 2], &s2, &c2);
    sincosf(psp[4 * lane + 3], &s3, &c3);
    const float o0r = x0r * c0 - x0i * s0, o0i = x0r * s0 + x0i * c0;
    const float o1r = x1r * c1 - x1i * s1, o1i = x1r * s1 + x1i * c1;
    const float o2r = x2r * c2 - x2i * s2, o2i = x2r * s2 + x2i * c2;
    const float o3r = x3r * c3 - x3i * s3, o3i = x3r * s3 + x3i * c3;
    float4* op = (float4*)out;
    const size_t base = (size_t)row * 64 + lane;
    op[base] = make_float4(o0r, o1r, o2r, o3r);
    op[(size_t)NB * 64 + base] = make_float4(o0i, o1i, o2i, o3i);
  }
}

// ---- ws-too-small fallback: direct raw kernel (validated lineage) ----------
__global__ __launch_bounds__(256) void mesh_raw_kernel(
    const float* __restrict__ xr_in, const float* __restrict__ xi_in,
    const void* __restrict__ pp0, const void* __restrict__ pp1,
    const void* __restrict__ pi0, const void* __restrict__ pi1,
    const float* __restrict__ psp, float* __restrict__ out) {
  const int lane = threadIdx.x & 63;
  const int wv   = threadIdx.x >> 6;
  const int row  = blockIdx.x * 4 + wv;
  const float4 r4 = ((const float4*)(xr_in + (size_t)row * NF))[lane];
  const float4 i4 = ((const float4*)(xi_in + (size_t)row * NF))[lane];
  float x0r = r4.x, x1r = r4.y, x2r = r4.z, x3r = r4.w;
  float x0i = i4.x, x1i = i4.y, x2i = i4.z, x3i = i4.w;
  const float* params = looks_zero(pp0) ? (const float*)pp1 : (const float*)pp0;
  const float* split  = looks_zero(pp0) ? (const float*)pp0 : (const float*)pp1;
  const float* atten  = looks_ones(pi0) ? (const float*)pi0 : (const float*)pi1;
#pragma unroll 1
  for (int s = 0; s < NSUB; s += 4) {
    for (int q = 0; q < 2; ++q) {
      Coef k = makeCoefRaw(params, split, atten, s + q, lane);
      mzi(x0r, x0i, x1r, x1i, k.a);
      mzi(x2r, x2i, x3r, x3i, k.b);
      x0r *= k.c.x; x0i *= k.c.x; x1r *= k.c.y; x1i *= k.c.y;
      x2r *= k.c.z; x2i *= k.c.z; x3r *= k.c.w; x3i *= k.c.w;
    }
    for (int q = 2; q < 4; ++q) {
      Coef k = makeCoefRaw(params, split, atten, s + q, lane);
      mzi(x1r, x1i, x2r, x2i, k.a);
      const float nvr = __shfl_down(x0r, 1);
      const float nvi = __shfl_down(x0i, 1);
      const float c = k.b.x, sv = k.b.y, t = k.b.z, r = k.b.w;
      const float pr  = c * x3r - sv * x3i;
      const float pi_ = sv * x3r + c * x3i;
      const float yur = t * pr  - r * nvi;
      const float yui = t * pi_ + r * nvr;
      const float yvr = t * nvr - r * pi_;
      const float yvi = t * nvi + r * pr;
      const float svr = __shfl_up(yvr, 1);
      const float svi = __shfl_up(yvi, 1);
      if (lane < 63) { x3r = yur; x3i = yui; }
      if (lane > 0)  { x0r = svr; x0i = svi; }
      x0r *= k.c.x; x0i *= k.c.x; x1r *= k.c.y; x1i *= k.c.y;
      x2r *= k.c.z; x2i *= k.c.z; x3r *= k.c.w; x3i *= k.c.w;
    }
  }
  float c0, s0, c1, s1, c2, s2, c3, s3;
  sincosf(psp[4 * lane + 0], &s0, &c0);
  sincosf(psp[4 * lane + 1], &s1, &c1);
  sincosf(psp[4 * lane + 2], &s2, &c2);
  sincosf(psp[4 * lane + 3], &s3, &c3);
  const float o0r = x0r * c0 - x0i * s0, o0i = x0r * s0 + x0i * c0;
  const float o1r = x1r * c1 - x1i * s1, o1i = x1r * s1 + x1i * c1;
  const float o2r = x2r * c2 - x2i * s2, o2i = x2r * s2 + x2i * c2;
  const float o3r = x3r * c3 - x3i * s3, o3i = x3r * s3 + x3i * c3;
  float4* op = (float4*)out;
  const size_t base = (size_t)row * 64 + lane;
  op[base] = make_float4(o0r, o1r, o2r, o3r);
  op[(size_t)NB * 64 + base] = make_float4(o0i, o1i, o2i, o3i);
}

extern "C" void kernel_launch(void* const* d_in, const int* in_sizes, int n_in,
                              void* d_out, int out_size, void* d_ws, size_t ws_size,
                              hipStream_t stream) {
  // Inputs resolved by element count + on-device content probes (R6-R10).
  const void* px[2] = { d_in[0], d_in[1] };
  const void* pp[2] = { d_in[2], d_in[5] };
  const void* pi2[2] = { d_in[4], d_in[6] };
  const void* pps = d_in[3];
  {
    const void* sx[2]; const void* sp[2]; const void* si[2];
    const void* s256 = nullptr;
    int nx = 0, npp = 0, ni = 0;
    for (int i = 0; i < n_in; ++i) {
      const int sz = in_sizes[i];
      if (sz == 262144 && nx < 2)      sx[nx++] = d_in[i];
      else if (sz == 65536 && npp < 2) sp[npp++] = d_in[i];
      else if (sz == 131072 && ni < 2) si[ni++] = d_in[i];
      else if (sz == 256)              s256 = d_in[i];
    }
    if (nx == 2)  { px[0] = sx[0];  px[1] = sx[1]; }
    if (npp == 2) { pp[0] = sp[0];  pp[1] = sp[1]; }
    if (ni == 2)  { pi2[0] = si[0]; pi2[1] = si[1]; }
    if (s256)     pps = s256;
  }
  float* out = (float*)d_out;

  if (ws_size >= WS_REQ) {
    float* ws = (float*)d_ws;
    flag_init_kernel<<<1, 1, 0, stream>>>(ws);
    check_kernel<<<512, 256, 0, stream>>>(pp[0], pp[1], pi2[0], pi2[1], ws);
    precompute3_kernel<<<NITER + 1, 256, 0, stream>>>(pp[0], pp[1],
                                                      (const float*)pps, ws);
    mesh3_kernel<<<NB / 4, 256, 0, stream>>>(
        (const float*)px[0], (const float*)px[1], ws,
        pp[0], pp[1], pi2[0], pi2[1], (const float*)pps, out);
  } else {
    mesh_raw_kernel<<<NB / 4, 256, 0, stream>>>(
        (const float*)px[0], (const float*)px[1],
        pp[0], pp[1], pi2[0], pi2[1], (const float*)pps, out);
  }
}